// Round 19
// baseline (157.351 us; speedup 1.0000x reference)
//
#include <hip/hip_runtime.h>
#include <cmath>

#define NCH   256
#define NPIX  3136
#define NB    32
#define SEV   7
#define INV_N (1.0f / 3136.0f)

typedef __attribute__((ext_vector_type(8)))  short bf16x8;
typedef __attribute__((ext_vector_type(4)))  float f32x4;
typedef __attribute__((ext_vector_type(16))) float f32x16;

// ws layout (float offsets)
#define KV7_F  (SEV * NB * 8 * 1024)   // 1,835,008
#define KM7_F  (SEV * NB * 256)        // 57,344
#define KVF_F  (NB * 8 * 1024)         // 262,144
#define KMF_F  (NB * 256)              // 8,192
#define KM7_OFF (KV7_F)
#define KVF_OFF (KM7_OFF + KM7_F)
#define KMF_OFF (KVF_OFF + KVF_F)
#define WF_OFF  (KMF_OFF + KMF_F)      // ushort region (16B aligned)

__device__ __forceinline__ ushort f2bf(float f) {
  unsigned u = __float_as_uint(f);
  u += 0x7FFFu + ((u >> 16) & 1u);
  return (ushort)(u >> 16);
}
__device__ __forceinline__ float bf2f(ushort h) {
  return __uint_as_float(((unsigned)h) << 16);
}

// ---------------------------------------------------------------------------
// Prep: qk_w (512x128) -> MFMA A-fragment layout, bf16 hi/lo split.
// ---------------------------------------------------------------------------
__global__ void wfrag_kernel(const float* __restrict__ qk_w, ushort* __restrict__ Wf) {
  const int tid = blockIdx.x * 512 + threadIdx.x;   // 0..16383
  const int lane = tid & 63;
  const int ks = (tid >> 6) & 3;
  const int mt = (tid >> 8) & 15;
  const int hl = (tid >> 12) & 1;
  const int side = (tid >> 13) & 1;
  const int ch = mt * 16 + (lane & 15);
  const int oc = side * 256 + ch;
  ushort v[8];
#pragma unroll
  for (int j = 0; j < 8; ++j) {
    const int k = ks * 32 + (lane >> 4) * 8 + j;
    const float w = qk_w[(size_t)oc * 128 + k];
    const ushort hi = f2bf(w);
    v[j] = (hl == 0) ? hi : f2bf(w - bf2f(hi));
  }
  *(uint4*)(Wf + (size_t)tid * 8) = *(const uint4*)v;
}

// ---------------------------------------------------------------------------
// Kernel P (v5): depthwise 3x3 pe conv, PURE STORE out = pe(x). Runs FIRST.
// r13's validated LDS-staged structure (dense coalesced f4 x staging — the
// fast-BW access pattern) minus the out-RMW read. Wave = (channel, row-half),
// lane = column; conflict-free LDS taps.
// ---------------------------------------------------------------------------
__global__ __launch_bounds__(512, 3)
void pe_kernel(const float* __restrict__ x, const float* __restrict__ pe_w,
               const float* __restrict__ pe_b, float* __restrict__ out) {
  const int b = blockIdx.y;
  const int c0 = blockIdx.x * 4;
  const int t = threadIdx.x;
  const int wave = t >> 6;
  const int cl = wave & 3;      // channel within block
  const int rh = wave >> 2;     // row half: rows rh*28 .. +28
  const int lane = t & 63;      // lane -> column (56 active)

  __shared__ float xs[4][NPIX];   // 50 KB

  // stage 4 channel images, dense coalesced float4 (the fast pattern)
#pragma unroll
  for (int cc = 0; cc < 4; ++cc) {
    const float4* src = (const float4*)(x + ((size_t)(b * NCH + c0 + cc)) * NPIX);
    float4* dst = (float4*)&xs[cc][0];
    for (int i = t; i < NPIX / 4; i += 512) dst[i] = src[i];
  }
  __syncthreads();

  const int c = c0 + cl;
  float pw[9];
#pragma unroll
  for (int i = 0; i < 9; ++i) pw[i] = pe_w[c * 9 + i];
  const float pb = pe_b[c];
  float* oc = out + ((size_t)(b * NCH + c)) * NPIX;
  const float* xc = xs[cl];

  if (lane < 56) {
    const bool hasL = (lane > 0), hasR = (lane < 55);
    for (int rg = 0; rg < 7; ++rg) {
      const int rbase = rh * 28 + rg * 4;
      float o[4];
#pragma unroll
      for (int k = 0; k < 4; ++k) {
        const int r = rbase + k;
        float s = pb;
#pragma unroll
        for (int dy = -1; dy <= 1; ++dy) {
          const int rr = r + dy;
          if (rr < 0 || rr >= 56) continue;   // wave-uniform
          const float* xrow = xc + rr * 56 + lane;
          if (hasL) s += pw[(dy + 1) * 3 + 0] * xrow[-1];
          s += pw[(dy + 1) * 3 + 1] * xrow[0];
          if (hasR) s += pw[(dy + 1) * 3 + 2] * xrow[1];
        }
        o[k] = s;
      }
#pragma unroll
      for (int k = 0; k < 4; ++k) oc[(rbase + k) * 56 + lane] = o[k];
    }
  }
}

// ---------------------------------------------------------------------------
// Kernel A (v11, validated ~35 us): head-split grid 448 = (hd, sev, b).
// ---------------------------------------------------------------------------
__global__ __launch_bounds__(512, 4)
void kv_kernel(const float* __restrict__ x, const ushort* __restrict__ Wf,
               const float* __restrict__ qk_b, float* __restrict__ kv7,
               float* __restrict__ km7) {
  const int bid = blockIdx.x;
  const int hd = (bid >= 224) ? 1 : 0;
  const int rem = bid - hd * 224;
  const int sev = rem >> 5, b = rem & 31;
  const int t = threadIdx.x;
  const int w = t >> 6, l = t & 63;
  const int q = l >> 4, r15 = l & 15;
  const int e = l & 31, q5 = l >> 5;
  const int h_l = w & 3, ph = w >> 2;
  const int mt = w;

  __shared__ __align__(16) ushort Xb[64][152];
  __shared__ __align__(16) ushort KVs[2 * 128 * 88];
  ushort (*Kst)[88] = (ushort(*)[88])KVs;
  ushort (*Vst)[88] = (ushort(*)[88])(KVs + 128 * 88);

  bf16x8 wf[4][2];
#pragma unroll
  for (int ks = 0; ks < 4; ++ks)
#pragma unroll
    for (int hl = 0; hl < 2; ++hl) {
      const size_t off =
          (size_t)(((((2 + hl) * 16 + (hd * 8 + mt)) * 4 + ks) * 64 + l)) * 8;
      wf[ks][hl] = *(const bf16x8*)(Wf + off);
    }

  float bias[4];
#pragma unroll
  for (int r = 0; r < 4; ++r)
    bias[r] = qk_b[256 + hd * 128 + mt * 16 + q * 4 + r];

  f32x16 kvacc;
#pragma unroll
  for (int i = 0; i < 16; ++i) kvacc[i] = 0.f;
  float kmacc[4] = {0.f, 0.f, 0.f, 0.f};

  const float* xk = x + ((size_t)(b * NCH) + 128) * NPIX + sev * 448;
  const float* xv = x + ((size_t)(b * NCH)) * NPIX + sev * 448;

  for (int st = 0; st < SEV; ++st) {
    const int p0 = st * 64;
    __syncthreads();

#pragma unroll
    for (int rr = 0; rr < 4; ++rr) {
      const int id = t + 512 * rr;
      const int cc = id >> 4;
      const int pf = id & 15;
      const float4 v = *(const float4*)(xk + (size_t)cc * NPIX + p0 + pf * 4);
      const ushort b0 = f2bf(v.x), b1 = f2bf(v.y), b2 = f2bf(v.z), b3 = f2bf(v.w);
      Xb[pf * 4 + 0][cc] = b0;
      Xb[pf * 4 + 1][cc] = b1;
      Xb[pf * 4 + 2][cc] = b2;
      Xb[pf * 4 + 3][cc] = b3;
      if (hd == 1) {
        const uint2 pk = {(uint)b0 | ((uint)b1 << 16), (uint)b2 | ((uint)b3 << 16)};
        *(uint2*)&Vst[cc][pf * 4] = pk;
      }
    }
    if (hd == 0) {
#pragma unroll
      for (int rr = 0; rr < 4; ++rr) {
        const int id = t + 512 * rr;
        const int cc = id >> 4;
        const int pf = id & 15;
        const float4 v = *(const float4*)(xv + (size_t)cc * NPIX + p0 + pf * 4);
        const uint2 pk = {(uint)f2bf(v.x) | ((uint)f2bf(v.y) << 16),
                          (uint)f2bf(v.z) | ((uint)f2bf(v.w) << 16)};
        *(uint2*)&Vst[cc][pf * 4] = pk;
      }
    }
    __syncthreads();

    f32x4 acc[4];
#pragma unroll
    for (int nt = 0; nt < 4; ++nt)
#pragma unroll
      for (int r = 0; r < 4; ++r) acc[nt][r] = 0.f;
#pragma unroll
    for (int ks = 0; ks < 4; ++ks) {
      bf16x8 xbf[4];
#pragma unroll
      for (int nt = 0; nt < 4; ++nt)
        xbf[nt] = *(const bf16x8*)&Xb[nt * 16 + r15][ks * 32 + q * 8];
#pragma unroll
      for (int nt = 0; nt < 4; ++nt) {
        acc[nt] = __builtin_amdgcn_mfma_f32_16x16x32_bf16(wf[ks][0], xbf[nt], acc[nt], 0, 0, 0);
        acc[nt] = __builtin_amdgcn_mfma_f32_16x16x32_bf16(wf[ks][1], xbf[nt], acc[nt], 0, 0, 0);
      }
    }

#pragma unroll
    for (int nt = 0; nt < 4; ++nt) {
#pragma unroll
      for (int r = 0; r < 4; ++r) {
        float v = acc[nt][r] + bias[r];
        v = (v > 0.f) ? (v + 1.f) : __expf(v);
        kmacc[r] += v;
        Kst[mt * 16 + q * 4 + r][nt * 16 + r15] = f2bf(v);
      }
    }
    __syncthreads();

#pragma unroll
    for (int ks2 = 0; ks2 < 2; ++ks2) {
      const int kp = ph * 32 + ks2 * 16 + q5 * 8;
      const bf16x8 ak = *(const bf16x8*)&Kst[h_l * 32 + e][kp];
      const bf16x8 bv = *(const bf16x8*)&Vst[h_l * 32 + e][kp];
      kvacc = __builtin_amdgcn_mfma_f32_32x32x16_bf16(ak, bv, kvacc, 0, 0, 0);
    }
  }

  __syncthreads();
  float* red = (float*)KVs;
#pragma unroll
  for (int reg = 0; reg < 16; ++reg) {
    const int row = (reg & 3) + 8 * (reg >> 2) + 4 * q5;
    red[w * 1024 + row * 32 + e] = kvacc[reg];
  }
  __syncthreads();
#pragma unroll
  for (int i = 0; i < 8; ++i) {
    const int idx = t + 512 * i;
    const int hl2 = idx >> 10;
    const int el = idx & 1023;
    const float s = red[hl2 * 1024 + el] + red[(hl2 + 4) * 1024 + el];
    kv7[(((size_t)sev * NB + b) * 8 + hd * 4 + hl2) * 1024 + el] = s;
  }
#pragma unroll
  for (int r = 0; r < 4; ++r) {
    float s = kmacc[r];
    s += __shfl_xor(s, 1);
    s += __shfl_xor(s, 2);
    s += __shfl_xor(s, 4);
    s += __shfl_xor(s, 8);
    if (r15 == 0)
      km7[((size_t)sev * NB + b) * 256 + hd * 128 + mt * 16 + q * 4 + r] = s;
  }
}

// ---------------------------------------------------------------------------
// Reduce: sum 7 partials, scale by 1/n.
// ---------------------------------------------------------------------------
__global__ void red_kernel(const float* __restrict__ kv7, const float* __restrict__ km7,
                           float* __restrict__ kvF, float* __restrict__ kmF) {
  const int b = blockIdx.x;
  const int t = threadIdx.x;
  for (int i = t; i < 8192; i += 256) {
    float s = 0.f;
#pragma unroll
    for (int sv = 0; sv < SEV; ++sv)
      s += kv7[(size_t)(sv * NB + b) * 8192 + i];
    kvF[(size_t)b * 8192 + i] = s * INV_N;
  }
  {
    float s = 0.f;
#pragma unroll
    for (int sv = 0; sv < SEV; ++sv)
      s += km7[(size_t)(sv * NB + b) * 256 + t];
    kmF[b * 256 + t] = s * INV_N;
  }
}

// ---------------------------------------------------------------------------
// Kernel B (v13 + RMW): channel-half split, grid 448, 2 blocks/CU.
// Stores ADD into out (pe already there; RMW read is L3-served).
// ---------------------------------------------------------------------------
__global__ __launch_bounds__(512, 4)
void out_kernel(const float* __restrict__ x, const ushort* __restrict__ Wf,
                const float* __restrict__ qk_b, const float* __restrict__ kvF,
                const float* __restrict__ kmF, float* __restrict__ out) {
  const int bid = blockIdx.x;
  const int hd = (bid >= 224) ? 1 : 0;   // paired blocks share bid%8 -> XCD
  const int rem = bid - hd * 224;
  const int b = rem & 31, sev = rem >> 5;
  const int t = threadIdx.x;
  const int w = t >> 6, l = t & 63;
  const int q = l >> 4, r15 = l & 15;
  const int mt = w;                      // conv: Mtile (16 Q-channels)
  const int h_l = w & 3, eh = w >> 2;    // num: local head, e-half

  __shared__ ushort Xb[64][136];
  __shared__ ushort QT[64][136];         // [pos][q-ch local 0..127]
  __shared__ float denP[8][64];          // per-Mtile den partials

  bf16x8 wf[4][2];
#pragma unroll
  for (int ks = 0; ks < 4; ++ks)
#pragma unroll
    for (int hl = 0; hl < 2; ++hl) {
      const size_t off =
          (size_t)((((hl * 16 + (hd * 8 + mt)) * 4 + ks) * 64 + l)) * 8;
      wf[ks][hl] = *(const bf16x8*)(Wf + off);
    }

  float bias[4], kmw[4];
#pragma unroll
  for (int r = 0; r < 4; ++r) {
    const int c = hd * 128 + mt * 16 + q * 4 + r;
    bias[r] = qk_b[c];
    kmw[r] = kmF[b * 256 + c];
  }

  bf16x8 bkv;
  {
    const int hg = hd * 4 + h_l;
#pragma unroll
    for (int j = 0; j < 8; ++j)
      bkv[j] = (short)f2bf(
          kvF[(size_t)b * 8192 + hg * 1024 + (q * 8 + j) * 32 + eh * 16 + r15]);
  }

  const float* xq = x + (size_t)(b * NCH) * NPIX + sev * 448;

  for (int st = 0; st < SEV; ++st) {
    const int pos0 = st * 64;
#pragma unroll
    for (int rr = 0; rr < 4; ++rr) {
      const int id = t + 512 * rr;
      const int ch = id >> 4;
      const int p4 = (id & 15) * 4;
      const float4 v = *(const float4*)(xq + (size_t)ch * NPIX + pos0 + p4);
      Xb[p4 + 0][ch] = f2bf(v.x);
      Xb[p4 + 1][ch] = f2bf(v.y);
      Xb[p4 + 2][ch] = f2bf(v.z);
      Xb[p4 + 3][ch] = f2bf(v.w);
    }
    __syncthreads();

    f32x4 acc[4];
#pragma unroll
    for (int nt = 0; nt < 4; ++nt)
#pragma unroll
      for (int r = 0; r < 4; ++r) acc[nt][r] = 0.f;
#pragma unroll
    for (int ks = 0; ks < 4; ++ks) {
      bf16x8 xbf[4];
#pragma unroll
      for (int nt = 0; nt < 4; ++nt)
        xbf[nt] = *(const bf16x8*)&Xb[nt * 16 + r15][ks * 32 + q * 8];
#pragma unroll
      for (int nt = 0; nt < 4; ++nt) {
        acc[nt] = __builtin_amdgcn_mfma_f32_16x16x32_bf16(wf[ks][0], xbf[nt], acc[nt], 0, 0, 0);
        acc[nt] = __builtin_amdgcn_mfma_f32_16x16x32_bf16(wf[ks][1], xbf[nt], acc[nt], 0, 0, 0);
      }
    }

#pragma unroll
    for (int nt = 0; nt < 4; ++nt) {
      ushort pk[4];
      float dsum = 0.f;
#pragma unroll
      for (int r = 0; r < 4; ++r) {
        float v = acc[nt][r] + bias[r];
        v = (v > 0.f) ? (v + 1.f) : __expf(v);
        pk[r] = f2bf(v);
        dsum += v * kmw[r];
      }
      *(uint2*)&QT[nt * 16 + r15][mt * 16 + q * 4] = *(const uint2*)pk;
      dsum += __shfl_xor(dsum, 16);
      dsum += __shfl_xor(dsum, 32);
      if (q == 0) denP[mt][nt * 16 + r15] = dsum;
    }
    __syncthreads();

#pragma unroll
    for (int pt = 0; pt < 4; ++pt) {
      const bf16x8 aq = *(const bf16x8*)&QT[pt * 16 + r15][h_l * 32 + q * 8];
      f32x4 z;
      z[0] = z[1] = z[2] = z[3] = 0.f;
      const f32x4 n0 = __builtin_amdgcn_mfma_f32_16x16x32_bf16(aq, bkv, z, 0, 0, 0);
      float rdn[4];
#pragma unroll
      for (int r = 0; r < 4; ++r) {
        const int pl = pt * 16 + q * 4 + r;
        rdn[r] = 1.0f / (denP[2 * h_l][pl] + denP[2 * h_l + 1][pl] + 1e-6f);
      }
      const int posg = sev * 448 + pos0 + pt * 16 + q * 4;
      const int c = hd * 128 + h_l * 32 + eh * 16 + r15;
      float* op = out + ((size_t)(b * NCH + c)) * NPIX + posg;
      float4 prev = *(const float4*)op;
      prev.x += n0[0] * rdn[0];
      prev.y += n0[1] * rdn[1];
      prev.z += n0[2] * rdn[2];
      prev.w += n0[3] * rdn[3];
      *(float4*)op = prev;
    }
    __syncthreads();   // QT/denP reuse next subtile
  }
}

extern "C" void kernel_launch(void* const* d_in, const int* in_sizes, int n_in,
                              void* d_out, int out_size, void* d_ws,
                              size_t ws_size, hipStream_t stream) {
  const float* x    = (const float*)d_in[0];
  const float* qk_w = (const float*)d_in[1];
  const float* qk_b = (const float*)d_in[2];
  const float* pe_w = (const float*)d_in[3];
  const float* pe_b = (const float*)d_in[4];
  float* out = (float*)d_out;

  float* wsf = (float*)d_ws;
  float* kv7 = wsf;
  float* km7 = wsf + KM7_OFF;
  float* kvF = wsf + KVF_OFF;
  float* kmF = wsf + KMF_OFF;
  ushort* Wf = (ushort*)(wsf + WF_OFF);

  dim3 gp(64, NB);
  pe_kernel<<<gp, 512, 0, stream>>>(x, pe_w, pe_b, out);   // pe FIRST (pure store)
  wfrag_kernel<<<32, 512, 0, stream>>>(qk_w, Wf);
  kv_kernel<<<448, 512, 0, stream>>>(x, Wf, qk_b, kv7, km7);
  red_kernel<<<NB, 256, 0, stream>>>(kv7, km7, kvF, kmF);
  out_kernel<<<448, 512, 0, stream>>>(x, Wf, qk_b, kvF, kmF, out);  // RMW add
}

// Round 20
// 144.828 us; speedup vs baseline: 1.0865x; 1.0865x over previous
//
#include <hip/hip_runtime.h>
#include <cmath>

#define NCH   256
#define NPIX  3136
#define NB    32
#define SEV   7
#define INV_N (1.0f / 3136.0f)

typedef __attribute__((ext_vector_type(8)))  short bf16x8;
typedef __attribute__((ext_vector_type(4)))  float f32x4;
typedef __attribute__((ext_vector_type(16))) float f32x16;

// ws layout (float offsets)
#define KV7_F  (SEV * NB * 8 * 1024)   // 1,835,008
#define KM7_F  (SEV * NB * 256)        // 57,344
#define KVF_F  (NB * 8 * 1024)         // 262,144
#define KMF_F  (NB * 256)              // 8,192
#define KM7_OFF (KV7_F)
#define KVF_OFF (KM7_OFF + KM7_F)
#define KMF_OFF (KVF_OFF + KVF_F)
#define WF_OFF  (KMF_OFF + KMF_F)      // ushort region (16B aligned)

__device__ __forceinline__ ushort f2bf(float f) {
  unsigned u = __float_as_uint(f);
  u += 0x7FFFu + ((u >> 16) & 1u);
  return (ushort)(u >> 16);
}
__device__ __forceinline__ float bf2f(ushort h) {
  return __uint_as_float(((unsigned)h) << 16);
}

// ---------------------------------------------------------------------------
// Prep: qk_w (512x128) -> MFMA A-fragment layout, bf16 hi/lo split.
// ---------------------------------------------------------------------------
__global__ void wfrag_kernel(const float* __restrict__ qk_w, ushort* __restrict__ Wf) {
  const int tid = blockIdx.x * 512 + threadIdx.x;   // 0..16383
  const int lane = tid & 63;
  const int ks = (tid >> 6) & 3;
  const int mt = (tid >> 8) & 15;
  const int hl = (tid >> 12) & 1;
  const int side = (tid >> 13) & 1;
  const int ch = mt * 16 + (lane & 15);
  const int oc = side * 256 + ch;
  ushort v[8];
#pragma unroll
  for (int j = 0; j < 8; ++j) {
    const int k = ks * 32 + (lane >> 4) * 8 + j;
    const float w = qk_w[(size_t)oc * 128 + k];
    const ushort hi = f2bf(w);
    v[j] = (hl == 0) ? hi : f2bf(w - bf2f(hi));
  }
  *(uint4*)(Wf + (size_t)tid * 8) = *(const uint4*)v;
}

// ---------------------------------------------------------------------------
// Kernel A+P (v20): kv v11 main + pe TAIL phase. Grid 448 = (hd, sev, b)
// tiles (channel-half, 8-row band, batch) disjointly; each block pe-stores
// out = pe(x) for exactly its 128 channels x 8 rows (f32 exact, no-shfl
// halo-window loads, no LDS). Block stagger overlaps pe memory phases with
// other blocks' kv MFMA phases on the same CU.
// ---------------------------------------------------------------------------
__global__ __launch_bounds__(512, 4)
void kvpe_kernel(const float* __restrict__ x, const ushort* __restrict__ Wf,
                 const float* __restrict__ qk_b, const float* __restrict__ pe_w,
                 const float* __restrict__ pe_b, float* __restrict__ kv7,
                 float* __restrict__ km7, float* __restrict__ out) {
  const int bid = blockIdx.x;
  const int hd = (bid >= 224) ? 1 : 0;
  const int rem = bid - hd * 224;
  const int sev = rem >> 5, b = rem & 31;
  const int t = threadIdx.x;
  const int w = t >> 6, l = t & 63;
  const int q = l >> 4, r15 = l & 15;
  const int e = l & 31, q5 = l >> 5;
  const int h_l = w & 3, ph = w >> 2;
  const int mt = w;

  __shared__ __align__(16) ushort Xb[64][152];
  __shared__ __align__(16) ushort KVs[2 * 128 * 88];
  ushort (*Kst)[88] = (ushort(*)[88])KVs;
  ushort (*Vst)[88] = (ushort(*)[88])(KVs + 128 * 88);

  bf16x8 wf[4][2];
#pragma unroll
  for (int ks = 0; ks < 4; ++ks)
#pragma unroll
    for (int hl = 0; hl < 2; ++hl) {
      const size_t off =
          (size_t)(((((2 + hl) * 16 + (hd * 8 + mt)) * 4 + ks) * 64 + l)) * 8;
      wf[ks][hl] = *(const bf16x8*)(Wf + off);
    }

  float bias[4];
#pragma unroll
  for (int r = 0; r < 4; ++r)
    bias[r] = qk_b[256 + hd * 128 + mt * 16 + q * 4 + r];

  f32x16 kvacc;
#pragma unroll
  for (int i = 0; i < 16; ++i) kvacc[i] = 0.f;
  float kmacc[4] = {0.f, 0.f, 0.f, 0.f};

  const float* xk = x + ((size_t)(b * NCH) + 128) * NPIX + sev * 448;
  const float* xv = x + ((size_t)(b * NCH)) * NPIX + sev * 448;

  for (int st = 0; st < SEV; ++st) {
    const int p0 = st * 64;
    __syncthreads();

#pragma unroll
    for (int rr = 0; rr < 4; ++rr) {
      const int id = t + 512 * rr;
      const int cc = id >> 4;
      const int pf = id & 15;
      const float4 v = *(const float4*)(xk + (size_t)cc * NPIX + p0 + pf * 4);
      const ushort b0 = f2bf(v.x), b1 = f2bf(v.y), b2 = f2bf(v.z), b3 = f2bf(v.w);
      Xb[pf * 4 + 0][cc] = b0;
      Xb[pf * 4 + 1][cc] = b1;
      Xb[pf * 4 + 2][cc] = b2;
      Xb[pf * 4 + 3][cc] = b3;
      if (hd == 1) {
        const uint2 pk = {(uint)b0 | ((uint)b1 << 16), (uint)b2 | ((uint)b3 << 16)};
        *(uint2*)&Vst[cc][pf * 4] = pk;
      }
    }
    if (hd == 0) {
#pragma unroll
      for (int rr = 0; rr < 4; ++rr) {
        const int id = t + 512 * rr;
        const int cc = id >> 4;
        const int pf = id & 15;
        const float4 v = *(const float4*)(xv + (size_t)cc * NPIX + p0 + pf * 4);
        const uint2 pk = {(uint)f2bf(v.x) | ((uint)f2bf(v.y) << 16),
                          (uint)f2bf(v.z) | ((uint)f2bf(v.w) << 16)};
        *(uint2*)&Vst[cc][pf * 4] = pk;
      }
    }
    __syncthreads();

    f32x4 acc[4];
#pragma unroll
    for (int nt = 0; nt < 4; ++nt)
#pragma unroll
      for (int r = 0; r < 4; ++r) acc[nt][r] = 0.f;
#pragma unroll
    for (int ks = 0; ks < 4; ++ks) {
      bf16x8 xbf[4];
#pragma unroll
      for (int nt = 0; nt < 4; ++nt)
        xbf[nt] = *(const bf16x8*)&Xb[nt * 16 + r15][ks * 32 + q * 8];
#pragma unroll
      for (int nt = 0; nt < 4; ++nt) {
        acc[nt] = __builtin_amdgcn_mfma_f32_16x16x32_bf16(wf[ks][0], xbf[nt], acc[nt], 0, 0, 0);
        acc[nt] = __builtin_amdgcn_mfma_f32_16x16x32_bf16(wf[ks][1], xbf[nt], acc[nt], 0, 0, 0);
      }
    }

#pragma unroll
    for (int nt = 0; nt < 4; ++nt) {
#pragma unroll
      for (int r = 0; r < 4; ++r) {
        float v = acc[nt][r] + bias[r];
        v = (v > 0.f) ? (v + 1.f) : __expf(v);
        kmacc[r] += v;
        Kst[mt * 16 + q * 4 + r][nt * 16 + r15] = f2bf(v);
      }
    }
    __syncthreads();

#pragma unroll
    for (int ks2 = 0; ks2 < 2; ++ks2) {
      const int kp = ph * 32 + ks2 * 16 + q5 * 8;
      const bf16x8 ak = *(const bf16x8*)&Kst[h_l * 32 + e][kp];
      const bf16x8 bv = *(const bf16x8*)&Vst[h_l * 32 + e][kp];
      kvacc = __builtin_amdgcn_mfma_f32_32x32x16_bf16(ak, bv, kvacc, 0, 0, 0);
    }
  }

  __syncthreads();
  float* red = (float*)KVs;
#pragma unroll
  for (int reg = 0; reg < 16; ++reg) {
    const int row = (reg & 3) + 8 * (reg >> 2) + 4 * q5;
    red[w * 1024 + row * 32 + e] = kvacc[reg];
  }
  __syncthreads();
#pragma unroll
  for (int i = 0; i < 8; ++i) {
    const int idx = t + 512 * i;
    const int hl2 = idx >> 10;
    const int el = idx & 1023;
    const float s = red[hl2 * 1024 + el] + red[(hl2 + 4) * 1024 + el];
    kv7[(((size_t)sev * NB + b) * 8 + hd * 4 + hl2) * 1024 + el] = s;
  }
#pragma unroll
  for (int r = 0; r < 4; ++r) {
    float s = kmacc[r];
    s += __shfl_xor(s, 1);
    s += __shfl_xor(s, 2);
    s += __shfl_xor(s, 4);
    s += __shfl_xor(s, 8);
    if (r15 == 0)
      km7[((size_t)sev * NB + b) * 256 + hd * 128 + mt * 16 + q * 4 + r] = s;
  }

  // ======== pe TAIL: channels hd*128 + w*16 .. +16, rows sev*8 .. +8 ========
  const bool pact = (l < 56);
  const int c4 = pact ? (l % 14) : 0;
  const int rq = pact ? (l / 14) : 0;
  const int col = c4 * 4;
  const int aoff = c4 ? (col - 1) : 0;
  const int boff = (c4 < 13) ? (col + 1) : col;
  const int row0 = sev * 8 + rq * 2;       // 2 output rows per lane
  const float4 Z = {0.f, 0.f, 0.f, 0.f};

  for (int ci = 0; ci < 16; ++ci) {
    const int c = hd * 128 + w * 16 + ci;
    const float* xc = x + ((size_t)(b * NCH + c)) * NPIX;
    float* oc = out + ((size_t)(b * NCH + c)) * NPIX;
    float pw[9];
#pragma unroll
    for (int i = 0; i < 9; ++i) pw[i] = pe_w[c * 9 + i];
    const float pb = pe_b[c];

    // xr[j][k] = x[row0-1+j][col-1+k], zero-padded at image borders
    float xr[4][6];
#pragma unroll
    for (int j = 0; j < 4; ++j) {
      const int rr = row0 - 1 + j;
      const bool vr = (rr >= 0) && (rr < 56);
      float4 A = Z, B = Z;
      if (vr) {
        A = *(const float4*)(xc + rr * 56 + aoff);
        B = *(const float4*)(xc + rr * 56 + boff);
      }
      xr[j][0] = c4 ? A.x : 0.f;
      xr[j][1] = c4 ? A.y : A.x;
      xr[j][2] = c4 ? A.z : A.y;
      xr[j][3] = c4 ? A.w : A.z;
      xr[j][4] = c4 ? ((c4 < 13) ? B.z : B.w) : A.w;
      xr[j][5] = (c4 < 13) ? B.w : 0.f;
    }

#pragma unroll
    for (int k = 0; k < 2; ++k) {
      float res[4];
#pragma unroll
      for (int i = 0; i < 4; ++i) {
        float s = pb;
#pragma unroll
        for (int dy = 0; dy < 3; ++dy) {
          s += pw[dy * 3 + 0] * xr[k + dy][i] +
               pw[dy * 3 + 1] * xr[k + dy][i + 1] +
               pw[dy * 3 + 2] * xr[k + dy][i + 2];
        }
        res[i] = s;
      }
      if (pact) {
        const float4 r4 = {res[0], res[1], res[2], res[3]};
        *(float4*)(oc + (row0 + k) * 56 + col) = r4;
      }
    }
  }
}

// ---------------------------------------------------------------------------
// Reduce: sum 7 partials, scale by 1/n.
// ---------------------------------------------------------------------------
__global__ void red_kernel(const float* __restrict__ kv7, const float* __restrict__ km7,
                           float* __restrict__ kvF, float* __restrict__ kmF) {
  const int b = blockIdx.x;
  const int t = threadIdx.x;
  for (int i = t; i < 8192; i += 256) {
    float s = 0.f;
#pragma unroll
    for (int sv = 0; sv < SEV; ++sv)
      s += kv7[(size_t)(sv * NB + b) * 8192 + i];
    kvF[(size_t)b * 8192 + i] = s * INV_N;
  }
  {
    float s = 0.f;
#pragma unroll
    for (int sv = 0; sv < SEV; ++sv)
      s += km7[(size_t)(sv * NB + b) * 256 + t];
    kmF[b * 256 + t] = s * INV_N;
  }
}

// ---------------------------------------------------------------------------
// Kernel B (v13 + RMW): channel-half split, grid 448, 2 blocks/CU.
// Stores ADD into out (pe already there; RMW read is L3-served).
// ---------------------------------------------------------------------------
__global__ __launch_bounds__(512, 4)
void out_kernel(const float* __restrict__ x, const ushort* __restrict__ Wf,
                const float* __restrict__ qk_b, const float* __restrict__ kvF,
                const float* __restrict__ kmF, float* __restrict__ out) {
  const int bid = blockIdx.x;
  const int hd = (bid >= 224) ? 1 : 0;   // paired blocks share bid%8 -> XCD
  const int rem = bid - hd * 224;
  const int b = rem & 31, sev = rem >> 5;
  const int t = threadIdx.x;
  const int w = t >> 6, l = t & 63;
  const int q = l >> 4, r15 = l & 15;
  const int mt = w;                      // conv: Mtile (16 Q-channels)
  const int h_l = w & 3, eh = w >> 2;    // num: local head, e-half

  __shared__ ushort Xb[64][136];
  __shared__ ushort QT[64][136];         // [pos][q-ch local 0..127]
  __shared__ float denP[8][64];          // per-Mtile den partials

  bf16x8 wf[4][2];
#pragma unroll
  for (int ks = 0; ks < 4; ++ks)
#pragma unroll
    for (int hl = 0; hl < 2; ++hl) {
      const size_t off =
          (size_t)((((hl * 16 + (hd * 8 + mt)) * 4 + ks) * 64 + l)) * 8;
      wf[ks][hl] = *(const bf16x8*)(Wf + off);
    }

  float bias[4], kmw[4];
#pragma unroll
  for (int r = 0; r < 4; ++r) {
    const int c = hd * 128 + mt * 16 + q * 4 + r;
    bias[r] = qk_b[c];
    kmw[r] = kmF[b * 256 + c];
  }

  bf16x8 bkv;
  {
    const int hg = hd * 4 + h_l;
#pragma unroll
    for (int j = 0; j < 8; ++j)
      bkv[j] = (short)f2bf(
          kvF[(size_t)b * 8192 + hg * 1024 + (q * 8 + j) * 32 + eh * 16 + r15]);
  }

  const float* xq = x + (size_t)(b * NCH) * NPIX + sev * 448;

  for (int st = 0; st < SEV; ++st) {
    const int pos0 = st * 64;
#pragma unroll
    for (int rr = 0; rr < 4; ++rr) {
      const int id = t + 512 * rr;
      const int ch = id >> 4;
      const int p4 = (id & 15) * 4;
      const float4 v = *(const float4*)(xq + (size_t)ch * NPIX + pos0 + p4);
      Xb[p4 + 0][ch] = f2bf(v.x);
      Xb[p4 + 1][ch] = f2bf(v.y);
      Xb[p4 + 2][ch] = f2bf(v.z);
      Xb[p4 + 3][ch] = f2bf(v.w);
    }
    __syncthreads();

    f32x4 acc[4];
#pragma unroll
    for (int nt = 0; nt < 4; ++nt)
#pragma unroll
      for (int r = 0; r < 4; ++r) acc[nt][r] = 0.f;
#pragma unroll
    for (int ks = 0; ks < 4; ++ks) {
      bf16x8 xbf[4];
#pragma unroll
      for (int nt = 0; nt < 4; ++nt)
        xbf[nt] = *(const bf16x8*)&Xb[nt * 16 + r15][ks * 32 + q * 8];
#pragma unroll
      for (int nt = 0; nt < 4; ++nt) {
        acc[nt] = __builtin_amdgcn_mfma_f32_16x16x32_bf16(wf[ks][0], xbf[nt], acc[nt], 0, 0, 0);
        acc[nt] = __builtin_amdgcn_mfma_f32_16x16x32_bf16(wf[ks][1], xbf[nt], acc[nt], 0, 0, 0);
      }
    }

#pragma unroll
    for (int nt = 0; nt < 4; ++nt) {
      ushort pk[4];
      float dsum = 0.f;
#pragma unroll
      for (int r = 0; r < 4; ++r) {
        float v = acc[nt][r] + bias[r];
        v = (v > 0.f) ? (v + 1.f) : __expf(v);
        pk[r] = f2bf(v);
        dsum += v * kmw[r];
      }
      *(uint2*)&QT[nt * 16 + r15][mt * 16 + q * 4] = *(const uint2*)pk;
      dsum += __shfl_xor(dsum, 16);
      dsum += __shfl_xor(dsum, 32);
      if (q == 0) denP[mt][nt * 16 + r15] = dsum;
    }
    __syncthreads();

#pragma unroll
    for (int pt = 0; pt < 4; ++pt) {
      const bf16x8 aq = *(const bf16x8*)&QT[pt * 16 + r15][h_l * 32 + q * 8];
      f32x4 z;
      z[0] = z[1] = z[2] = z[3] = 0.f;
      const f32x4 n0 = __builtin_amdgcn_mfma_f32_16x16x32_bf16(aq, bkv, z, 0, 0, 0);
      float rdn[4];
#pragma unroll
      for (int r = 0; r < 4; ++r) {
        const int pl = pt * 16 + q * 4 + r;
        rdn[r] = 1.0f / (denP[2 * h_l][pl] + denP[2 * h_l + 1][pl] + 1e-6f);
      }
      const int posg = sev * 448 + pos0 + pt * 16 + q * 4;
      const int c = hd * 128 + h_l * 32 + eh * 16 + r15;
      float* op = out + ((size_t)(b * NCH + c)) * NPIX + posg;
      float4 prev = *(const float4*)op;
      prev.x += n0[0] * rdn[0];
      prev.y += n0[1] * rdn[1];
      prev.z += n0[2] * rdn[2];
      prev.w += n0[3] * rdn[3];
      *(float4*)op = prev;
    }
    __syncthreads();   // QT/denP reuse next subtile
  }
}

extern "C" void kernel_launch(void* const* d_in, const int* in_sizes, int n_in,
                              void* d_out, int out_size, void* d_ws,
                              size_t ws_size, hipStream_t stream) {
  const float* x    = (const float*)d_in[0];
  const float* qk_w = (const float*)d_in[1];
  const float* qk_b = (const float*)d_in[2];
  const float* pe_w = (const float*)d_in[3];
  const float* pe_b = (const float*)d_in[4];
  float* out = (float*)d_out;

  float* wsf = (float*)d_ws;
  float* kv7 = wsf;
  float* km7 = wsf + KM7_OFF;
  float* kvF = wsf + KVF_OFF;
  float* kmF = wsf + KMF_OFF;
  ushort* Wf = (ushort*)(wsf + WF_OFF);

  wfrag_kernel<<<32, 512, 0, stream>>>(qk_w, Wf);
  kvpe_kernel<<<448, 512, 0, stream>>>(x, Wf, qk_b, pe_w, pe_b, kv7, km7, out);
  red_kernel<<<NB, 256, 0, stream>>>(kv7, km7, kvF, kmF);
  out_kernel<<<448, 512, 0, stream>>>(x, Wf, qk_b, kvF, kmF, out);  // RMW add
}

// Round 21
// 143.972 us; speedup vs baseline: 1.0929x; 1.0059x over previous
//
#include <hip/hip_runtime.h>
#include <cmath>

#define NCH   256
#define NPIX  3136
#define NB    32
#define SEV   7
#define INV_N (1.0f / 3136.0f)

typedef __attribute__((ext_vector_type(8)))  short bf16x8;
typedef __attribute__((ext_vector_type(4)))  float f32x4;
typedef __attribute__((ext_vector_type(16))) float f32x16;

// ws layout (float offsets)
#define KV7_F  (SEV * NB * 8 * 1024)   // 1,835,008
#define KM7_F  (SEV * NB * 256)        // 57,344
#define KVF_F  (NB * 8 * 1024)         // 262,144
#define KMF_F  (NB * 256)              // 8,192
#define KM7_OFF (KV7_F)
#define KVF_OFF (KM7_OFF + KM7_F)
#define KMF_OFF (KVF_OFF + KVF_F)
#define WF_OFF  (KMF_OFF + KMF_F)      // ushort region (16B aligned)

__device__ __forceinline__ ushort f2bf(float f) {
  unsigned u = __float_as_uint(f);
  u += 0x7FFFu + ((u >> 16) & 1u);
  return (ushort)(u >> 16);
}
__device__ __forceinline__ float bf2f(ushort h) {
  return __uint_as_float(((unsigned)h) << 16);
}

// ---------------------------------------------------------------------------
// Prep: qk_w (512x128) -> MFMA A-fragment layout, bf16 hi/lo split.
// ---------------------------------------------------------------------------
__global__ void wfrag_kernel(const float* __restrict__ qk_w, ushort* __restrict__ Wf) {
  const int tid = blockIdx.x * 512 + threadIdx.x;   // 0..16383
  const int lane = tid & 63;
  const int ks = (tid >> 6) & 3;
  const int mt = (tid >> 8) & 15;
  const int hl = (tid >> 12) & 1;
  const int side = (tid >> 13) & 1;
  const int ch = mt * 16 + (lane & 15);
  const int oc = side * 256 + ch;
  ushort v[8];
#pragma unroll
  for (int j = 0; j < 8; ++j) {
    const int k = ks * 32 + (lane >> 4) * 8 + j;
    const float w = qk_w[(size_t)oc * 128 + k];
    const ushort hi = f2bf(w);
    v[j] = (hl == 0) ? hi : f2bf(w - bf2f(hi));
  }
  *(uint4*)(Wf + (size_t)tid * 8) = *(const uint4*)v;
}

// ---------------------------------------------------------------------------
// Kernel P (v6): depthwise 3x3 pe conv, PURE STORE out = pe(x). Runs FIRST.
// FLAT-QUAD mapping: lane t owns flat f4 quad p=4*(t+it*512) -> each wave
// STORE is 1024B contiguous (the 16B/lane coalescing sweet spot). Since
// 56 % 4 == 0 a quad never crosses a row. Loads = r18's in-bounds halo
// windows (6 f4 per quad, issued up-front). Block = 4 channels, grid 2048.
// ---------------------------------------------------------------------------
__global__ __launch_bounds__(512)
void pe_kernel(const float* __restrict__ x, const float* __restrict__ pe_w,
               const float* __restrict__ pe_b, float* __restrict__ out) {
  const int gb = blockIdx.x;           // 0..2047
  const int b = gb >> 6;
  const int c0 = (gb & 63) * 4;
  const int t = threadIdx.x;
  const float4 Z = {0.f, 0.f, 0.f, 0.f};

  for (int ci = 0; ci < 4; ++ci) {
    const int c = c0 + ci;
    const float* xc = x + ((size_t)(b * NCH + c)) * NPIX;
    float* oc = out + ((size_t)(b * NCH + c)) * NPIX;
    float pw[9];
#pragma unroll
    for (int i = 0; i < 9; ++i) pw[i] = pe_w[c * 9 + i];
    const float pb = pe_b[c];

#pragma unroll
    for (int it = 0; it < 2; ++it) {
      const int qi = t + it * 512;
      const bool qact = (qi < 784);          // 784 = 3136/4
      const int qs = qact ? qi : 783;        // clamp for safe addresses
      const int p = qs * 4;                  // flat f4 position (one row)
      const int c4 = (p % 56) >> 2;          // column quad 0..13
      const int aoff = c4 ? -1 : 0;
      const int boff = (c4 < 13) ? 1 : 0;

      // xr[j][k] = x[p + (j-1)*56 + k - 1], zero-padded at image borders
      float xr[3][6];
#pragma unroll
      for (int j = 0; j < 3; ++j) {
        const int pr = p + (j - 1) * 56;
        const bool vr = (pr >= 0) && (pr < NPIX);
        float4 A = Z, B = Z;
        if (vr) {
          A = *(const float4*)(xc + pr + aoff);
          B = *(const float4*)(xc + pr + boff);
        }
        xr[j][0] = c4 ? A.x : 0.f;
        xr[j][1] = c4 ? A.y : A.x;
        xr[j][2] = c4 ? A.z : A.y;
        xr[j][3] = c4 ? A.w : A.z;
        xr[j][4] = c4 ? ((c4 < 13) ? B.z : B.w) : A.w;
        xr[j][5] = (c4 < 13) ? B.w : 0.f;
      }

      float r_[4];
#pragma unroll
      for (int i = 0; i < 4; ++i) {
        float s = pb;
#pragma unroll
        for (int dy = 0; dy < 3; ++dy) {
          s += pw[dy * 3 + 0] * xr[dy][i] +
               pw[dy * 3 + 1] * xr[dy][i + 1] +
               pw[dy * 3 + 2] * xr[dy][i + 2];
        }
        r_[i] = s;
      }
      if (qact) {
        const float4 r4 = {r_[0], r_[1], r_[2], r_[3]};
        *(float4*)(oc + p) = r4;             // wave: 1KB contiguous store
      }
    }
  }
}

// ---------------------------------------------------------------------------
// Kernel A (v11, validated ~35 us): head-split grid 448 = (hd, sev, b).
// ---------------------------------------------------------------------------
__global__ __launch_bounds__(512, 4)
void kv_kernel(const float* __restrict__ x, const ushort* __restrict__ Wf,
               const float* __restrict__ qk_b, float* __restrict__ kv7,
               float* __restrict__ km7) {
  const int bid = blockIdx.x;
  const int hd = (bid >= 224) ? 1 : 0;
  const int rem = bid - hd * 224;
  const int sev = rem >> 5, b = rem & 31;
  const int t = threadIdx.x;
  const int w = t >> 6, l = t & 63;
  const int q = l >> 4, r15 = l & 15;
  const int e = l & 31, q5 = l >> 5;
  const int h_l = w & 3, ph = w >> 2;
  const int mt = w;

  __shared__ __align__(16) ushort Xb[64][152];
  __shared__ __align__(16) ushort KVs[2 * 128 * 88];
  ushort (*Kst)[88] = (ushort(*)[88])KVs;
  ushort (*Vst)[88] = (ushort(*)[88])(KVs + 128 * 88);

  bf16x8 wf[4][2];
#pragma unroll
  for (int ks = 0; ks < 4; ++ks)
#pragma unroll
    for (int hl = 0; hl < 2; ++hl) {
      const size_t off =
          (size_t)(((((2 + hl) * 16 + (hd * 8 + mt)) * 4 + ks) * 64 + l)) * 8;
      wf[ks][hl] = *(const bf16x8*)(Wf + off);
    }

  float bias[4];
#pragma unroll
  for (int r = 0; r < 4; ++r)
    bias[r] = qk_b[256 + hd * 128 + mt * 16 + q * 4 + r];

  f32x16 kvacc;
#pragma unroll
  for (int i = 0; i < 16; ++i) kvacc[i] = 0.f;
  float kmacc[4] = {0.f, 0.f, 0.f, 0.f};

  const float* xk = x + ((size_t)(b * NCH) + 128) * NPIX + sev * 448;
  const float* xv = x + ((size_t)(b * NCH)) * NPIX + sev * 448;

  for (int st = 0; st < SEV; ++st) {
    const int p0 = st * 64;
    __syncthreads();

#pragma unroll
    for (int rr = 0; rr < 4; ++rr) {
      const int id = t + 512 * rr;
      const int cc = id >> 4;
      const int pf = id & 15;
      const float4 v = *(const float4*)(xk + (size_t)cc * NPIX + p0 + pf * 4);
      const ushort b0 = f2bf(v.x), b1 = f2bf(v.y), b2 = f2bf(v.z), b3 = f2bf(v.w);
      Xb[pf * 4 + 0][cc] = b0;
      Xb[pf * 4 + 1][cc] = b1;
      Xb[pf * 4 + 2][cc] = b2;
      Xb[pf * 4 + 3][cc] = b3;
      if (hd == 1) {
        const uint2 pk = {(uint)b0 | ((uint)b1 << 16), (uint)b2 | ((uint)b3 << 16)};
        *(uint2*)&Vst[cc][pf * 4] = pk;
      }
    }
    if (hd == 0) {
#pragma unroll
      for (int rr = 0; rr < 4; ++rr) {
        const int id = t + 512 * rr;
        const int cc = id >> 4;
        const int pf = id & 15;
        const float4 v = *(const float4*)(xv + (size_t)cc * NPIX + p0 + pf * 4);
        const uint2 pk = {(uint)f2bf(v.x) | ((uint)f2bf(v.y) << 16),
                          (uint)f2bf(v.z) | ((uint)f2bf(v.w) << 16)};
        *(uint2*)&Vst[cc][pf * 4] = pk;
      }
    }
    __syncthreads();

    f32x4 acc[4];
#pragma unroll
    for (int nt = 0; nt < 4; ++nt)
#pragma unroll
      for (int r = 0; r < 4; ++r) acc[nt][r] = 0.f;
#pragma unroll
    for (int ks = 0; ks < 4; ++ks) {
      bf16x8 xbf[4];
#pragma unroll
      for (int nt = 0; nt < 4; ++nt)
        xbf[nt] = *(const bf16x8*)&Xb[nt * 16 + r15][ks * 32 + q * 8];
#pragma unroll
      for (int nt = 0; nt < 4; ++nt) {
        acc[nt] = __builtin_amdgcn_mfma_f32_16x16x32_bf16(wf[ks][0], xbf[nt], acc[nt], 0, 0, 0);
        acc[nt] = __builtin_amdgcn_mfma_f32_16x16x32_bf16(wf[ks][1], xbf[nt], acc[nt], 0, 0, 0);
      }
    }

#pragma unroll
    for (int nt = 0; nt < 4; ++nt) {
#pragma unroll
      for (int r = 0; r < 4; ++r) {
        float v = acc[nt][r] + bias[r];
        v = (v > 0.f) ? (v + 1.f) : __expf(v);
        kmacc[r] += v;
        Kst[mt * 16 + q * 4 + r][nt * 16 + r15] = f2bf(v);
      }
    }
    __syncthreads();

#pragma unroll
    for (int ks2 = 0; ks2 < 2; ++ks2) {
      const int kp = ph * 32 + ks2 * 16 + q5 * 8;
      const bf16x8 ak = *(const bf16x8*)&Kst[h_l * 32 + e][kp];
      const bf16x8 bv = *(const bf16x8*)&Vst[h_l * 32 + e][kp];
      kvacc = __builtin_amdgcn_mfma_f32_32x32x16_bf16(ak, bv, kvacc, 0, 0, 0);
    }
  }

  __syncthreads();
  float* red = (float*)KVs;
#pragma unroll
  for (int reg = 0; reg < 16; ++reg) {
    const int row = (reg & 3) + 8 * (reg >> 2) + 4 * q5;
    red[w * 1024 + row * 32 + e] = kvacc[reg];
  }
  __syncthreads();
#pragma unroll
  for (int i = 0; i < 8; ++i) {
    const int idx = t + 512 * i;
    const int hl2 = idx >> 10;
    const int el = idx & 1023;
    const float s = red[hl2 * 1024 + el] + red[(hl2 + 4) * 1024 + el];
    kv7[(((size_t)sev * NB + b) * 8 + hd * 4 + hl2) * 1024 + el] = s;
  }
#pragma unroll
  for (int r = 0; r < 4; ++r) {
    float s = kmacc[r];
    s += __shfl_xor(s, 1);
    s += __shfl_xor(s, 2);
    s += __shfl_xor(s, 4);
    s += __shfl_xor(s, 8);
    if (r15 == 0)
      km7[((size_t)sev * NB + b) * 256 + hd * 128 + mt * 16 + q * 4 + r] = s;
  }
}

// ---------------------------------------------------------------------------
// Reduce: sum 7 partials, scale by 1/n.
// ---------------------------------------------------------------------------
__global__ void red_kernel(const float* __restrict__ kv7, const float* __restrict__ km7,
                           float* __restrict__ kvF, float* __restrict__ kmF) {
  const int b = blockIdx.x;
  const int t = threadIdx.x;
  for (int i = t; i < 8192; i += 256) {
    float s = 0.f;
#pragma unroll
    for (int sv = 0; sv < SEV; ++sv)
      s += kv7[(size_t)(sv * NB + b) * 8192 + i];
    kvF[(size_t)b * 8192 + i] = s * INV_N;
  }
  {
    float s = 0.f;
#pragma unroll
    for (int sv = 0; sv < SEV; ++sv)
      s += km7[(size_t)(sv * NB + b) * 256 + t];
    kmF[b * 256 + t] = s * INV_N;
  }
}

// ---------------------------------------------------------------------------
// Kernel B (v13 + RMW): channel-half split, grid 448, 2 blocks/CU.
// Stores ADD into out (pe already there; RMW read is L3-served).
// ---------------------------------------------------------------------------
__global__ __launch_bounds__(512, 4)
void out_kernel(const float* __restrict__ x, const ushort* __restrict__ Wf,
                const float* __restrict__ qk_b, const float* __restrict__ kvF,
                const float* __restrict__ kmF, float* __restrict__ out) {
  const int bid = blockIdx.x;
  const int hd = (bid >= 224) ? 1 : 0;   // paired blocks share bid%8 -> XCD
  const int rem = bid - hd * 224;
  const int b = rem & 31, sev = rem >> 5;
  const int t = threadIdx.x;
  const int w = t >> 6, l = t & 63;
  const int q = l >> 4, r15 = l & 15;
  const int mt = w;                      // conv: Mtile (16 Q-channels)
  const int h_l = w & 3, eh = w >> 2;    // num: local head, e-half

  __shared__ ushort Xb[64][136];
  __shared__ ushort QT[64][136];         // [pos][q-ch local 0..127]
  __shared__ float denP[8][64];          // per-Mtile den partials

  bf16x8 wf[4][2];
#pragma unroll
  for (int ks = 0; ks < 4; ++ks)
#pragma unroll
    for (int hl = 0; hl < 2; ++hl) {
      const size_t off =
          (size_t)((((hl * 16 + (hd * 8 + mt)) * 4 + ks) * 64 + l)) * 8;
      wf[ks][hl] = *(const bf16x8*)(Wf + off);
    }

  float bias[4], kmw[4];
#pragma unroll
  for (int r = 0; r < 4; ++r) {
    const int c = hd * 128 + mt * 16 + q * 4 + r;
    bias[r] = qk_b[c];
    kmw[r] = kmF[b * 256 + c];
  }

  bf16x8 bkv;
  {
    const int hg = hd * 4 + h_l;
#pragma unroll
    for (int j = 0; j < 8; ++j)
      bkv[j] = (short)f2bf(
          kvF[(size_t)b * 8192 + hg * 1024 + (q * 8 + j) * 32 + eh * 16 + r15]);
  }

  const float* xq = x + (size_t)(b * NCH) * NPIX + sev * 448;

  for (int st = 0; st < SEV; ++st) {
    const int pos0 = st * 64;
#pragma unroll
    for (int rr = 0; rr < 4; ++rr) {
      const int id = t + 512 * rr;
      const int ch = id >> 4;
      const int p4 = (id & 15) * 4;
      const float4 v = *(const float4*)(xq + (size_t)ch * NPIX + pos0 + p4);
      Xb[p4 + 0][ch] = f2bf(v.x);
      Xb[p4 + 1][ch] = f2bf(v.y);
      Xb[p4 + 2][ch] = f2bf(v.z);
      Xb[p4 + 3][ch] = f2bf(v.w);
    }
    __syncthreads();

    f32x4 acc[4];
#pragma unroll
    for (int nt = 0; nt < 4; ++nt)
#pragma unroll
      for (int r = 0; r < 4; ++r) acc[nt][r] = 0.f;
#pragma unroll
    for (int ks = 0; ks < 4; ++ks) {
      bf16x8 xbf[4];
#pragma unroll
      for (int nt = 0; nt < 4; ++nt)
        xbf[nt] = *(const bf16x8*)&Xb[nt * 16 + r15][ks * 32 + q * 8];
#pragma unroll
      for (int nt = 0; nt < 4; ++nt) {
        acc[nt] = __builtin_amdgcn_mfma_f32_16x16x32_bf16(wf[ks][0], xbf[nt], acc[nt], 0, 0, 0);
        acc[nt] = __builtin_amdgcn_mfma_f32_16x16x32_bf16(wf[ks][1], xbf[nt], acc[nt], 0, 0, 0);
      }
    }

#pragma unroll
    for (int nt = 0; nt < 4; ++nt) {
      ushort pk[4];
      float dsum = 0.f;
#pragma unroll
      for (int r = 0; r < 4; ++r) {
        float v = acc[nt][r] + bias[r];
        v = (v > 0.f) ? (v + 1.f) : __expf(v);
        pk[r] = f2bf(v);
        dsum += v * kmw[r];
      }
      *(uint2*)&QT[nt * 16 + r15][mt * 16 + q * 4] = *(const uint2*)pk;
      dsum += __shfl_xor(dsum, 16);
      dsum += __shfl_xor(dsum, 32);
      if (q == 0) denP[mt][nt * 16 + r15] = dsum;
    }
    __syncthreads();

#pragma unroll
    for (int pt = 0; pt < 4; ++pt) {
      const bf16x8 aq = *(const bf16x8*)&QT[pt * 16 + r15][h_l * 32 + q * 8];
      f32x4 z;
      z[0] = z[1] = z[2] = z[3] = 0.f;
      const f32x4 n0 = __builtin_amdgcn_mfma_f32_16x16x32_bf16(aq, bkv, z, 0, 0, 0);
      float rdn[4];
#pragma unroll
      for (int r = 0; r < 4; ++r) {
        const int pl = pt * 16 + q * 4 + r;
        rdn[r] = 1.0f / (denP[2 * h_l][pl] + denP[2 * h_l + 1][pl] + 1e-6f);
      }
      const int posg = sev * 448 + pos0 + pt * 16 + q * 4;
      const int c = hd * 128 + h_l * 32 + eh * 16 + r15;
      float* op = out + ((size_t)(b * NCH + c)) * NPIX + posg;
      float4 prev = *(const float4*)op;
      prev.x += n0[0] * rdn[0];
      prev.y += n0[1] * rdn[1];
      prev.z += n0[2] * rdn[2];
      prev.w += n0[3] * rdn[3];
      *(float4*)op = prev;
    }
    __syncthreads();   // QT/denP reuse next subtile
  }
}

extern "C" void kernel_launch(void* const* d_in, const int* in_sizes, int n_in,
                              void* d_out, int out_size, void* d_ws,
                              size_t ws_size, hipStream_t stream) {
  const float* x    = (const float*)d_in[0];
  const float* qk_w = (const float*)d_in[1];
  const float* qk_b = (const float*)d_in[2];
  const float* pe_w = (const float*)d_in[3];
  const float* pe_b = (const float*)d_in[4];
  float* out = (float*)d_out;

  float* wsf = (float*)d_ws;
  float* kv7 = wsf;
  float* km7 = wsf + KM7_OFF;
  float* kvF = wsf + KVF_OFF;
  float* kmF = wsf + KMF_OFF;
  ushort* Wf = (ushort*)(wsf + WF_OFF);

  pe_kernel<<<2048, 512, 0, stream>>>(x, pe_w, pe_b, out);   // pe FIRST (pure store)
  wfrag_kernel<<<32, 512, 0, stream>>>(qk_w, Wf);
  kv_kernel<<<448, 512, 0, stream>>>(x, Wf, qk_b, kv7, km7);
  red_kernel<<<NB, 256, 0, stream>>>(kv7, km7, kvF, kmF);
  out_kernel<<<448, 512, 0, stream>>>(x, Wf, qk_b, kvF, kmF, out);  // RMW add
}

// Round 22
// 138.582 us; speedup vs baseline: 1.1354x; 1.0389x over previous
//
#include <hip/hip_runtime.h>
#include <cmath>

#define NCH   256
#define NPIX  3136
#define NB    32
#define SEV   7
#define INV_N (1.0f / 3136.0f)

typedef __attribute__((ext_vector_type(8)))  short bf16x8;
typedef __attribute__((ext_vector_type(4)))  float f32x4;
typedef __attribute__((ext_vector_type(16))) float f32x16;

// ws layout (float offsets)
#define KV7_F  (SEV * NB * 8 * 1024)   // 1,835,008
#define KM7_F  (SEV * NB * 256)        // 57,344
#define KVF_F  (NB * 8 * 1024)         // 262,144
#define KMF_F  (NB * 256)              // 8,192
#define KM7_OFF (KV7_F)
#define KVF_OFF (KM7_OFF + KM7_F)
#define KMF_OFF (KVF_OFF + KVF_F)
#define WF_OFF  (KMF_OFF + KMF_F)      // ushort region (16B aligned)

__device__ __forceinline__ ushort f2bf(float f) {
  unsigned u = __float_as_uint(f);
  u += 0x7FFFu + ((u >> 16) & 1u);
  return (ushort)(u >> 16);
}
__device__ __forceinline__ float bf2f(ushort h) {
  return __uint_as_float(((unsigned)h) << 16);
}

// ---------------------------------------------------------------------------
// Prep: qk_w (512x128) -> MFMA A-fragment layout, bf16 hi/lo split.
// ---------------------------------------------------------------------------
__global__ void wfrag_kernel(const float* __restrict__ qk_w, ushort* __restrict__ Wf) {
  const int tid = blockIdx.x * 512 + threadIdx.x;   // 0..16383
  const int lane = tid & 63;
  const int ks = (tid >> 6) & 3;
  const int mt = (tid >> 8) & 15;
  const int hl = (tid >> 12) & 1;
  const int side = (tid >> 13) & 1;
  const int ch = mt * 16 + (lane & 15);
  const int oc = side * 256 + ch;
  ushort v[8];
#pragma unroll
  for (int j = 0; j < 8; ++j) {
    const int k = ks * 32 + (lane >> 4) * 8 + j;
    const float w = qk_w[(size_t)oc * 128 + k];
    const ushort hi = f2bf(w);
    v[j] = (hl == 0) ? hi : f2bf(w - bf2f(hi));
  }
  *(uint4*)(Wf + (size_t)tid * 8) = *(const uint4*)v;
}

// ---------------------------------------------------------------------------
// Kernel P (v2, validated 70 us in this slot): depthwise 3x3 pe conv,
// PURE STORE out = pe(x). Runs FIRST. Register-ring + shfl halos, no LDS.
// Wave = (channel, row-half).
// ---------------------------------------------------------------------------
__global__ __launch_bounds__(512)
void pe_kernel(const float* __restrict__ x, const float* __restrict__ pe_w,
               const float* __restrict__ pe_b, float* __restrict__ out) {
  const int b = blockIdx.y;
  const int t = threadIdx.x;
  const int w = t >> 6;
  const int cl = w & 3, rh = w >> 2;
  const int l = t & 63;
  const int c = blockIdx.x * 4 + cl;

  const float* xc = x + ((size_t)(b * NCH + c)) * NPIX;
  float* oc = out + ((size_t)(b * NCH + c)) * NPIX;

  float pw[9];
#pragma unroll
  for (int i = 0; i < 9; ++i) pw[i] = pe_w[c * 9 + i];
  const float pb = pe_b[c];

  const bool act = (l < 56);
  const int colv = act ? l : 55;
  const bool hasL = act && (l > 0);
  const bool hasR = (l < 55);
  const int lnL = (l + 63) & 63, lnR = (l + 1) & 63;
  const int r0 = rh * 28;

  // ring: rows r0-1 (m), r0 (c)
  float mC = (r0 > 0) ? xc[(r0 - 1) * 56 + colv] : 0.f;
  float cC = xc[r0 * 56 + colv];
  float mL = __shfl(mC, lnL), mR = __shfl(mC, lnR);
  float cL = __shfl(cC, lnL), cR = __shfl(cC, lnR);

#pragma unroll 4
  for (int r = 0; r < 28; ++r) {
    const int grp = r0 + r + 1;
    const float pCv = (grp < 56) ? xc[grp * 56 + colv] : 0.f;
    const float pL = __shfl(pCv, lnL);
    const float pR = __shfl(pCv, lnR);
    float s = pb + pw[1] * mC + pw[4] * cC + pw[7] * pCv;
    if (hasL) s += pw[0] * mL + pw[3] * cL + pw[6] * pL;
    if (hasR) s += pw[2] * mR + pw[5] * cR + pw[8] * pR;
    if (act) oc[(r0 + r) * 56 + l] = s;
    mC = cC; mL = cL; mR = cR;
    cC = pCv; cL = pL; cR = pR;
  }
}

// ---------------------------------------------------------------------------
// Kernel A (v11, validated ~35 us): head-split grid 448 = (hd, sev, b).
// ---------------------------------------------------------------------------
__global__ __launch_bounds__(512, 4)
void kv_kernel(const float* __restrict__ x, const ushort* __restrict__ Wf,
               const float* __restrict__ qk_b, float* __restrict__ kv7,
               float* __restrict__ km7) {
  const int bid = blockIdx.x;
  const int hd = (bid >= 224) ? 1 : 0;
  const int rem = bid - hd * 224;
  const int sev = rem >> 5, b = rem & 31;
  const int t = threadIdx.x;
  const int w = t >> 6, l = t & 63;
  const int q = l >> 4, r15 = l & 15;
  const int e = l & 31, q5 = l >> 5;
  const int h_l = w & 3, ph = w >> 2;
  const int mt = w;

  __shared__ __align__(16) ushort Xb[64][152];
  __shared__ __align__(16) ushort KVs[2 * 128 * 88];
  ushort (*Kst)[88] = (ushort(*)[88])KVs;
  ushort (*Vst)[88] = (ushort(*)[88])(KVs + 128 * 88);

  bf16x8 wf[4][2];
#pragma unroll
  for (int ks = 0; ks < 4; ++ks)
#pragma unroll
    for (int hl = 0; hl < 2; ++hl) {
      const size_t off =
          (size_t)(((((2 + hl) * 16 + (hd * 8 + mt)) * 4 + ks) * 64 + l)) * 8;
      wf[ks][hl] = *(const bf16x8*)(Wf + off);
    }

  float bias[4];
#pragma unroll
  for (int r = 0; r < 4; ++r)
    bias[r] = qk_b[256 + hd * 128 + mt * 16 + q * 4 + r];

  f32x16 kvacc;
#pragma unroll
  for (int i = 0; i < 16; ++i) kvacc[i] = 0.f;
  float kmacc[4] = {0.f, 0.f, 0.f, 0.f};

  const float* xk = x + ((size_t)(b * NCH) + 128) * NPIX + sev * 448;
  const float* xv = x + ((size_t)(b * NCH)) * NPIX + sev * 448;

  for (int st = 0; st < SEV; ++st) {
    const int p0 = st * 64;
    __syncthreads();

#pragma unroll
    for (int rr = 0; rr < 4; ++rr) {
      const int id = t + 512 * rr;
      const int cc = id >> 4;
      const int pf = id & 15;
      const float4 v = *(const float4*)(xk + (size_t)cc * NPIX + p0 + pf * 4);
      const ushort b0 = f2bf(v.x), b1 = f2bf(v.y), b2 = f2bf(v.z), b3 = f2bf(v.w);
      Xb[pf * 4 + 0][cc] = b0;
      Xb[pf * 4 + 1][cc] = b1;
      Xb[pf * 4 + 2][cc] = b2;
      Xb[pf * 4 + 3][cc] = b3;
      if (hd == 1) {
        const uint2 pk = {(uint)b0 | ((uint)b1 << 16), (uint)b2 | ((uint)b3 << 16)};
        *(uint2*)&Vst[cc][pf * 4] = pk;
      }
    }
    if (hd == 0) {
#pragma unroll
      for (int rr = 0; rr < 4; ++rr) {
        const int id = t + 512 * rr;
        const int cc = id >> 4;
        const int pf = id & 15;
        const float4 v = *(const float4*)(xv + (size_t)cc * NPIX + p0 + pf * 4);
        const uint2 pk = {(uint)f2bf(v.x) | ((uint)f2bf(v.y) << 16),
                          (uint)f2bf(v.z) | ((uint)f2bf(v.w) << 16)};
        *(uint2*)&Vst[cc][pf * 4] = pk;
      }
    }
    __syncthreads();

    f32x4 acc[4];
#pragma unroll
    for (int nt = 0; nt < 4; ++nt)
#pragma unroll
      for (int r = 0; r < 4; ++r) acc[nt][r] = 0.f;
#pragma unroll
    for (int ks = 0; ks < 4; ++ks) {
      bf16x8 xbf[4];
#pragma unroll
      for (int nt = 0; nt < 4; ++nt)
        xbf[nt] = *(const bf16x8*)&Xb[nt * 16 + r15][ks * 32 + q * 8];
#pragma unroll
      for (int nt = 0; nt < 4; ++nt) {
        acc[nt] = __builtin_amdgcn_mfma_f32_16x16x32_bf16(wf[ks][0], xbf[nt], acc[nt], 0, 0, 0);
        acc[nt] = __builtin_amdgcn_mfma_f32_16x16x32_bf16(wf[ks][1], xbf[nt], acc[nt], 0, 0, 0);
      }
    }

#pragma unroll
    for (int nt = 0; nt < 4; ++nt) {
#pragma unroll
      for (int r = 0; r < 4; ++r) {
        float v = acc[nt][r] + bias[r];
        v = (v > 0.f) ? (v + 1.f) : __expf(v);
        kmacc[r] += v;
        Kst[mt * 16 + q * 4 + r][nt * 16 + r15] = f2bf(v);
      }
    }
    __syncthreads();

#pragma unroll
    for (int ks2 = 0; ks2 < 2; ++ks2) {
      const int kp = ph * 32 + ks2 * 16 + q5 * 8;
      const bf16x8 ak = *(const bf16x8*)&Kst[h_l * 32 + e][kp];
      const bf16x8 bv = *(const bf16x8*)&Vst[h_l * 32 + e][kp];
      kvacc = __builtin_amdgcn_mfma_f32_32x32x16_bf16(ak, bv, kvacc, 0, 0, 0);
    }
  }

  __syncthreads();
  float* red = (float*)KVs;
#pragma unroll
  for (int reg = 0; reg < 16; ++reg) {
    const int row = (reg & 3) + 8 * (reg >> 2) + 4 * q5;
    red[w * 1024 + row * 32 + e] = kvacc[reg];
  }
  __syncthreads();
#pragma unroll
  for (int i = 0; i < 8; ++i) {
    const int idx = t + 512 * i;
    const int hl2 = idx >> 10;
    const int el = idx & 1023;
    const float s = red[hl2 * 1024 + el] + red[(hl2 + 4) * 1024 + el];
    kv7[(((size_t)sev * NB + b) * 8 + hd * 4 + hl2) * 1024 + el] = s;
  }
#pragma unroll
  for (int r = 0; r < 4; ++r) {
    float s = kmacc[r];
    s += __shfl_xor(s, 1);
    s += __shfl_xor(s, 2);
    s += __shfl_xor(s, 4);
    s += __shfl_xor(s, 8);
    if (r15 == 0)
      km7[((size_t)sev * NB + b) * 256 + hd * 128 + mt * 16 + q * 4 + r] = s;
  }
}

// ---------------------------------------------------------------------------
// Reduce: sum 7 partials, scale by 1/n.
// ---------------------------------------------------------------------------
__global__ void red_kernel(const float* __restrict__ kv7, const float* __restrict__ km7,
                           float* __restrict__ kvF, float* __restrict__ kmF) {
  const int b = blockIdx.x;
  const int t = threadIdx.x;
  for (int i = t; i < 8192; i += 256) {
    float s = 0.f;
#pragma unroll
    for (int sv = 0; sv < SEV; ++sv)
      s += kv7[(size_t)(sv * NB + b) * 8192 + i];
    kvF[(size_t)b * 8192 + i] = s * INV_N;
  }
  {
    float s = 0.f;
#pragma unroll
    for (int sv = 0; sv < SEV; ++sv)
      s += km7[(size_t)(sv * NB + b) * 256 + t];
    kmF[b * 256 + t] = s * INV_N;
  }
}

// ---------------------------------------------------------------------------
// Kernel B (v13 + RMW): channel-half split, grid 448, 2 blocks/CU.
// Stores ADD into out (pe already there; RMW read is L3-served).
// ---------------------------------------------------------------------------
__global__ __launch_bounds__(512, 4)
void out_kernel(const float* __restrict__ x, const ushort* __restrict__ Wf,
                const float* __restrict__ qk_b, const float* __restrict__ kvF,
                const float* __restrict__ kmF, float* __restrict__ out) {
  const int bid = blockIdx.x;
  const int hd = (bid >= 224) ? 1 : 0;   // paired blocks share bid%8 -> XCD
  const int rem = bid - hd * 224;
  const int b = rem & 31, sev = rem >> 5;
  const int t = threadIdx.x;
  const int w = t >> 6, l = t & 63;
  const int q = l >> 4, r15 = l & 15;
  const int mt = w;                      // conv: Mtile (16 Q-channels)
  const int h_l = w & 3, eh = w >> 2;    // num: local head, e-half

  __shared__ ushort Xb[64][136];
  __shared__ ushort QT[64][136];         // [pos][q-ch local 0..127]
  __shared__ float denP[8][64];          // per-Mtile den partials

  bf16x8 wf[4][2];
#pragma unroll
  for (int ks = 0; ks < 4; ++ks)
#pragma unroll
    for (int hl = 0; hl < 2; ++hl) {
      const size_t off =
          (size_t)((((hl * 16 + (hd * 8 + mt)) * 4 + ks) * 64 + l)) * 8;
      wf[ks][hl] = *(const bf16x8*)(Wf + off);
    }

  float bias[4], kmw[4];
#pragma unroll
  for (int r = 0; r < 4; ++r) {
    const int c = hd * 128 + mt * 16 + q * 4 + r;
    bias[r] = qk_b[c];
    kmw[r] = kmF[b * 256 + c];
  }

  bf16x8 bkv;
  {
    const int hg = hd * 4 + h_l;
#pragma unroll
    for (int j = 0; j < 8; ++j)
      bkv[j] = (short)f2bf(
          kvF[(size_t)b * 8192 + hg * 1024 + (q * 8 + j) * 32 + eh * 16 + r15]);
  }

  const float* xq = x + (size_t)(b * NCH) * NPIX + sev * 448;

  for (int st = 0; st < SEV; ++st) {
    const int pos0 = st * 64;
#pragma unroll
    for (int rr = 0; rr < 4; ++rr) {
      const int id = t + 512 * rr;
      const int ch = id >> 4;
      const int p4 = (id & 15) * 4;
      const float4 v = *(const float4*)(xq + (size_t)ch * NPIX + pos0 + p4);
      Xb[p4 + 0][ch] = f2bf(v.x);
      Xb[p4 + 1][ch] = f2bf(v.y);
      Xb[p4 + 2][ch] = f2bf(v.z);
      Xb[p4 + 3][ch] = f2bf(v.w);
    }
    __syncthreads();

    f32x4 acc[4];
#pragma unroll
    for (int nt = 0; nt < 4; ++nt)
#pragma unroll
      for (int r = 0; r < 4; ++r) acc[nt][r] = 0.f;
#pragma unroll
    for (int ks = 0; ks < 4; ++ks) {
      bf16x8 xbf[4];
#pragma unroll
      for (int nt = 0; nt < 4; ++nt)
        xbf[nt] = *(const bf16x8*)&Xb[nt * 16 + r15][ks * 32 + q * 8];
#pragma unroll
      for (int nt = 0; nt < 4; ++nt) {
        acc[nt] = __builtin_amdgcn_mfma_f32_16x16x32_bf16(wf[ks][0], xbf[nt], acc[nt], 0, 0, 0);
        acc[nt] = __builtin_amdgcn_mfma_f32_16x16x32_bf16(wf[ks][1], xbf[nt], acc[nt], 0, 0, 0);
      }
    }

#pragma unroll
    for (int nt = 0; nt < 4; ++nt) {
      ushort pk[4];
      float dsum = 0.f;
#pragma unroll
      for (int r = 0; r < 4; ++r) {
        float v = acc[nt][r] + bias[r];
        v = (v > 0.f) ? (v + 1.f) : __expf(v);
        pk[r] = f2bf(v);
        dsum += v * kmw[r];
      }
      *(uint2*)&QT[nt * 16 + r15][mt * 16 + q * 4] = *(const uint2*)pk;
      dsum += __shfl_xor(dsum, 16);
      dsum += __shfl_xor(dsum, 32);
      if (q == 0) denP[mt][nt * 16 + r15] = dsum;
    }
    __syncthreads();

#pragma unroll
    for (int pt = 0; pt < 4; ++pt) {
      const bf16x8 aq = *(const bf16x8*)&QT[pt * 16 + r15][h_l * 32 + q * 8];
      f32x4 z;
      z[0] = z[1] = z[2] = z[3] = 0.f;
      const f32x4 n0 = __builtin_amdgcn_mfma_f32_16x16x32_bf16(aq, bkv, z, 0, 0, 0);
      float rdn[4];
#pragma unroll
      for (int r = 0; r < 4; ++r) {
        const int pl = pt * 16 + q * 4 + r;
        rdn[r] = 1.0f / (denP[2 * h_l][pl] + denP[2 * h_l + 1][pl] + 1e-6f);
      }
      const int posg = sev * 448 + pos0 + pt * 16 + q * 4;
      const int c = hd * 128 + h_l * 32 + eh * 16 + r15;
      float* op = out + ((size_t)(b * NCH + c)) * NPIX + posg;
      float4 prev = *(const float4*)op;
      prev.x += n0[0] * rdn[0];
      prev.y += n0[1] * rdn[1];
      prev.z += n0[2] * rdn[2];
      prev.w += n0[3] * rdn[3];
      *(float4*)op = prev;
    }
    __syncthreads();   // QT/denP reuse next subtile
  }
}

extern "C" void kernel_launch(void* const* d_in, const int* in_sizes, int n_in,
                              void* d_out, int out_size, void* d_ws,
                              size_t ws_size, hipStream_t stream) {
  const float* x    = (const float*)d_in[0];
  const float* qk_w = (const float*)d_in[1];
  const float* qk_b = (const float*)d_in[2];
  const float* pe_w = (const float*)d_in[3];
  const float* pe_b = (const float*)d_in[4];
  float* out = (float*)d_out;

  float* wsf = (float*)d_ws;
  float* kv7 = wsf;
  float* km7 = wsf + KM7_OFF;
  float* kvF = wsf + KVF_OFF;
  float* kmF = wsf + KMF_OFF;
  ushort* Wf = (ushort*)(wsf + WF_OFF);

  dim3 gp(64, NB);
  pe_kernel<<<gp, 512, 0, stream>>>(x, pe_w, pe_b, out);   // pe FIRST (pure store)
  wfrag_kernel<<<32, 512, 0, stream>>>(qk_w, Wf);
  kv_kernel<<<448, 512, 0, stream>>>(x, Wf, qk_b, kv7, km7);
  red_kernel<<<NB, 256, 0, stream>>>(kv7, km7, kvF, kmF);
  out_kernel<<<448, 512, 0, stream>>>(x, Wf, qk_b, kvF, kmF, out);  // RMW add
}